// Round 2
// baseline (617.359 us; speedup 1.0000x reference)
//
#include <hip/hip_runtime.h>
#include <hip/hip_bf16.h>
#include <hip/hip_cooperative_groups.h>
#include <math.h>

namespace cg = cooperative_groups;

#define SS 4096
#define EE 1024
#define HH 16

typedef __bf16 bf16x8 __attribute__((ext_vector_type(8)));
typedef float  f32x4v __attribute__((ext_vector_type(4)));

// ws offsets (floats). total ~22.5 MB
#define OFF_QVEC 0L
#define OFF_QKB  1024L
#define OFF_QH   1040L      /* ushort[16*1024] = 8192 floats */
#define OFF_QL   9232L      /* ushort[16*1024] */
#define OFF_SEC  17424L     /* [8][16][256] = 32768 */
#define OFF_SAC  50192L     /* [8][16][256] = 32768 */
#define OFF_WG   82960L     /* [8][4096][16] = 524288 */
#define OFF_HID  607248L    /* 8192 */
#define OFF_T1   615440L    /* ushort[16*4096] = 32768 floats */
#define OFF_INVD 648208L    /* 128 */
#define OFF_PSUM 648336L    /* 128 */
#define OFF_PX   648464L    /* ushort[8][64][16][1024] = 4194304 floats */
#define OFF_GTH  4842768L   /* double[8*16*4096] = 1048576 floats (even offset -> 8B aligned) */

struct MP {
  const float *x, *gum, *query, *Wq, *bq, *Wk, *bk, *Wv, *bv, *lng, *lnb, *W1, *b1, *W2, *b2;
  float *qvec, *qkb, *seC, *saC, *Wg, *hid, *invD, *psum;
  double *gth;
  unsigned short *qh, *ql, *t1u, *px;
  float *out;
};

__device__ __forceinline__ float bf2f(unsigned int u){
  union { unsigned int i; float f; } c; c.i = u << 16; return c.f;
}
__device__ __forceinline__ unsigned int pk_hi(float a, float b){
  return __builtin_amdgcn_perm(__float_as_uint(b), __float_as_uint(a), 0x07060302u);
}
__device__ __forceinline__ float lo_part(float f){
  return f - __uint_as_float(__float_as_uint(f) & 0xFFFF0000u);
}
__device__ __forceinline__ unsigned short f2bf_rn(float f){
  unsigned int u = __float_as_uint(f);
  return (unsigned short)((u + 0x7fffu + ((u >> 16) & 1u)) >> 16);
}
__device__ __forceinline__ f32x4v mfma16(bf16x8 a, bf16x8 b, f32x4v c){
  return __builtin_amdgcn_mfma_f32_16x16x32_bf16(a, b, c, 0, 0, 0);
}
__device__ __forceinline__ float waveRedSum(float v){
  #pragma unroll
  for (int m=1;m<64;m<<=1) v += __shfl_xor(v, m, 64);
  return v;
}
template<int NW>
__device__ __forceinline__ float blockRedSum(float v, volatile float* scr){
  v = waveRedSum(v);
  const int w = threadIdx.x >> 6;
  __syncthreads();
  if ((threadIdx.x & 63) == 0) scr[w] = v;
  __syncthreads();
  float r = 0.f;
  #pragma unroll
  for (int i=0;i<NW;i++) r += scr[i];
  return r;
}

__device__ __forceinline__ double gdiff(float u0, float u1){
  const double g0 = -log(-log((double)u0 + 1e-20) + 1e-20);
  const double g1 = -log(-log((double)u1 + 1e-20) + 1e-20);
  return g0 - g1;   // keep element iff (double)logit > gdiff
}
__device__ __forceinline__ void ph_gth(const MP& p, long i0){
  const float4 a4 = *(const float4*)(p.gum + 2*i0);
  const float4 b4 = *(const float4*)(p.gum + 2*i0 + 4);
  p.gth[i0+0] = gdiff(a4.x, a4.y);
  p.gth[i0+1] = gdiff(a4.z, a4.w);
  p.gth[i0+2] = gdiff(b4.x, b4.y);
  p.gth[i0+3] = gdiff(b4.z, b4.w);
}

// ---------------- P0: qvec (blocks 0-255) | gth half 1 + hid zero + out=b2 (blocks 256-511) ----------------
__device__ void phase0(const MP& p, int bid, int t){
  const int wv = t >> 6, lane = t & 63;
  if (bid < 256){
    const int j = bid*4 + wv;
    float acc = 0.f;
    #pragma unroll
    for (int i=0;i<4;i++){
      const int e = 4*lane + 256*i;
      const float4 q4 = *(const float4*)(p.query + e);
      const float4 w4 = *(const float4*)(p.Wq + (long)j*EE + e);
      acc += q4.x*w4.x + q4.y*w4.y + q4.z*w4.z + q4.w*w4.w;
    }
    acc = waveRedSum(acc);
    if (lane == 0) p.qvec[j] = acc + p.bq[j];
  } else {
    const int ib = bid - 256;
    if (ib < 32) p.hid[ib*256 + t] = 0.f;
    else if (ib < 64) p.out[(ib-32)*256 + t] = p.b2[((ib-32)&3)*256 + t];
    ph_gth(p, (long)ib*1024 + t*4);
  }
}

// ---------------- P1: k2 qh/ql/qkb (blocks 0-255) | gth half 2 (blocks 256-511) ----------------
__device__ void phase1(const MP& p, int bid, int t, char* SMc){
  const int wv = t >> 6, lane = t & 63;
  if (bid < 256){
    float* red = (float*)SMc;          // [4][64]
    const int h = bid >> 4;
    const int e = (bid & 15)*64 + lane;
    float acc = 0.f;
    #pragma unroll
    for (int dd=0; dd<16; dd++){
      const int d = wv*16 + dd;
      acc += p.qvec[h*64+d] * p.Wk[(long)(h*64+d)*EE + e];
    }
    red[wv*64 + lane] = acc;
    __syncthreads();
    if (wv == 0){
      const float s = red[lane] + red[64+lane] + red[128+lane] + red[192+lane];
      const unsigned int ub = __float_as_uint(s);
      p.qh[h*EE + e] = (unsigned short)(ub >> 16);
      const float lo = s - __uint_as_float(ub & 0xFFFF0000u);
      p.ql[h*EE + e] = (unsigned short)(__float_as_uint(lo) >> 16);
      if ((bid & 15) == 0){
        float pr = p.qvec[h*64+lane] * p.bk[h*64+lane];
        pr = waveRedSum(pr);
        if (lane == 0) p.qkb[h] = pr;
      }
    }
  } else {
    ph_gth(p, 262144L + (long)(bid-256)*1024 + t*4);
  }
}

// ---------------- P2: logits MFMA + gumbel mask (precomputed gth) + chunk sums + aggregation MFMA ----------
__device__ void phase2(const MP& p, int bid, int t, char* SMc){
  unsigned short* xsT = (unsigned short*)SMc;        // [4][256*32] = 64 KB
  float* lg   = (float*)(SMc + 65536);               // [4*16*17]
  float* wT   = (float*)(SMc + 69888);               // [16][20]
  float* scrA = (float*)(SMc + 71168);               // [16*17]
  float* scrB = (float*)(SMc + 72256);               // [16*17]
  float* sQkb = (float*)(SMc + 73344);               // [16]
  const int wv = t >> 6, lane = t & 63;
  const int m16 = lane & 15, q = lane >> 4;
  const int blk = bid & 63, b = bid >> 6;
  if (t < 16) sQkb[t] = p.qkb[t];
  unsigned short* xw = xsT + wv*8192;

  f32x4v P[16];
  #pragma unroll
  for (int i=0;i<16;i++){ P[i][0]=0.f; P[i][1]=0.f; P[i][2]=0.f; P[i][3]=0.f; }

  for (int ch=0; ch<4; ch++){
    const int c = blk*4 + ch;
    const long xbase = ((long)(b*SS + c*16))*EE;

    // phase 1: logits via split-bf16 MFMA; stage exact bf16 halves transposed into LDS
    f32x4v a = {0.f,0.f,0.f,0.f};
    #pragma unroll
    for (int kt=0; kt<8; kt++){
      const int k = wv*256 + kt*32 + q*8;
      const float* xp = p.x + xbase + (long)m16*EE + k;
      const float4 f0 = *(const float4*)(xp);
      const float4 f1 = *(const float4*)(xp + 4);
      union { uint4 u; bf16x8 v; } xh, xl, bh, bl;
      xh.u.x = pk_hi(f0.x, f0.y); xh.u.y = pk_hi(f0.z, f0.w);
      xh.u.z = pk_hi(f1.x, f1.y); xh.u.w = pk_hi(f1.z, f1.w);
      xl.u.x = pk_hi(lo_part(f0.x), lo_part(f0.y)); xl.u.y = pk_hi(lo_part(f0.z), lo_part(f0.w));
      xl.u.z = pk_hi(lo_part(f1.x), lo_part(f1.y)); xl.u.w = pk_hi(lo_part(f1.z), lo_part(f1.w));
      bh.u = *(const uint4*)(p.qh + (long)m16*EE + k);
      bl.u = *(const uint4*)(p.ql + (long)m16*EE + k);
      a = mfma16(xh.v, bh.v, a);
      a = mfma16(xh.v, bl.v, a);
      a = mfma16(xl.v, bh.v, a);
      const int e0 = kt*32 + q*8;
      const unsigned hw[4] = {xh.u.x, xh.u.y, xh.u.z, xh.u.w};
      const unsigned lw[4] = {xl.u.x, xl.u.y, xl.u.z, xl.u.w};
      #pragma unroll
      for (int jj=0; jj<8; jj++){
        const unsigned sh = (jj & 1) * 16;
        xw[(e0+jj)*32 + m16]      = (unsigned short)(hw[jj>>1] >> sh);
        xw[(e0+jj)*32 + 16 + m16] = (unsigned short)(lw[jj>>1] >> sh);
      }
    }
    #pragma unroll
    for (int r=0;r<4;r++)
      lg[(wv*16 + q*4 + r)*17 + m16] = a[r];
    __syncthreads();

    // phase 2: logit assembly + precomputed gumbel threshold
    {
      const int h = t & 15, s = t >> 4;
      const float dot = lg[s*17+h] + lg[(16+s)*17+h] + lg[(32+s)*17+h] + lg[(48+s)*17+h];
      const float logit = (dot + sQkb[h]) * 0.125f;
      const long gi = ((long)(b*16 + h))*SS + c*16 + s;
      const double gthd = p.gth[gi];
      const float e = expf(logit);
      const float wval = ((double)logit > gthd) ? e : 0.f;
      wT[h*20 + s] = wval;
      p.Wg[((long)b*SS + c*16 + s)*16 + h] = wval;
      scrA[s*17 + h] = e;
      scrB[s*17 + h] = wval;
    }
    __syncthreads();

    // tail A: per-chunk sums + mask counts
    if (t < 16){
      float S = 0.f, SA = 0.f, cnt = 0.f;
      #pragma unroll
      for (int i=0;i<16;i++){ S += scrA[i*17 + t]; SA += scrB[i*17 + t]; }
      #pragma unroll
      for (int hh=0; hh<16; hh++) cnt += (scrB[t*17 + hh] > 0.f) ? 1.f : 0.f;
      p.seC[((long)(b*16 + t))*256 + c] = S;
      p.saC[((long)(b*16 + t))*256 + c] = SA;
      p.out[8192 + (long)b*SS + c*16 + t] = cnt;
    }

    // tail B: aggregation MFMA, exact via stacked hi/lo K=32
    {
      float wf[8];
      *(float4*)&wf[0] = *(const float4*)&wT[m16*20 + (q & 1)*8];
      *(float4*)&wf[4] = *(const float4*)&wT[m16*20 + (q & 1)*8 + 4];
      union { uint4 u; bf16x8 v; } B1, B2;
      B1.u.x = pk_hi(wf[0],wf[1]); B1.u.y = pk_hi(wf[2],wf[3]);
      B1.u.z = pk_hi(wf[4],wf[5]); B1.u.w = pk_hi(wf[6],wf[7]);
      B2.u.x = pk_hi(lo_part(wf[0]),lo_part(wf[1])); B2.u.y = pk_hi(lo_part(wf[2]),lo_part(wf[3]));
      B2.u.z = pk_hi(lo_part(wf[4]),lo_part(wf[5])); B2.u.w = pk_hi(lo_part(wf[6]),lo_part(wf[7]));
      #pragma unroll
      for (int et=0; et<16; et++){
        union { uint4 u; bf16x8 v; } A;
        A.u = *(const uint4*)(xw + (et*16 + m16)*32 + q*8);
        P[et] = mfma16(A.v, B1.v, P[et]);
        P[et] = mfma16(A.v, B2.v, P[et]);
      }
    }
  }

  // store bf16 partials: px[b][blk][h=m16][e = wv*256 + et*16 + q*4 + r]
  const long pbase = (((long)(b*64 + blk))*16 + m16)*1024 + wv*256;
  #pragma unroll
  for (int et=0; et<16; et++){
    uint2 pk2;
    pk2.x = (unsigned)f2bf_rn(P[et][0]) | ((unsigned)f2bf_rn(P[et][1]) << 16);
    pk2.y = (unsigned)f2bf_rn(P[et][2]) | ((unsigned)f2bf_rn(P[et][3]) << 16);
    *(uint2*)(p.px + pbase + et*16 + q*4) = pk2;
  }
}

// ---------------- P3: invD/psum + px reduce + hid = xa.Wv*invD + psum*bv (atomics) ----------------
__device__ void phase3(const MP& p, int bid, int t, char* SMc){
  float* scr1 = (float*)SMc;
  float* scr2 = scr1 + 16;
  float* xs   = scr1 + 32;
  const int b = bid >> 6, h = (bid >> 2) & 15, eq = bid & 3;
  const long rbase = ((long)(b*16 + h))*256;
  const float D    = blockRedSum<4>(p.seC[rbase + t], scr1);
  const float SA   = blockRedSum<4>(p.saC[rbase + t], scr2);
  const float invD = 1.f / D;
  const float psum = SA * invD;
  if (eq == 0 && t == 0){ p.invD[b*16+h] = invD; p.psum[b*16+h] = psum; }
  const unsigned short* pp = p.px + (((long)(b*64))*16 + h)*1024 + eq*256 + t;
  float xa = 0.f;
  #pragma unroll 8
  for (int seg=0; seg<64; seg++) xa += bf2f((unsigned)pp[(long)seg*16384]);
  xs[t] = xa;
  __syncthreads();
  const int wv = t >> 6, lane = t & 63;
  const float4 xv = *(const float4*)(xs + 4*lane);
  #pragma unroll 4
  for (int jj=0; jj<16; jj++){
    const int j = h*64 + wv*16 + jj;
    const float4 w4 = *(const float4*)(p.Wv + (long)j*EE + eq*256 + 4*lane);
    float pr = xv.x*w4.x + xv.y*w4.y + xv.z*w4.z + xv.w*w4.w;
    pr = waveRedSum(pr);
    if (lane == 0){
      float add = pr * invD;
      if (eq == 0) add += psum * p.bv[j];
      atomicAdd(&p.hid[(long)b*EE + j], add);
    }
  }
}

// ---------------- P4: LN + MLP1 (blocks 0-255) | attn out (blocks 256-511) ----------------
__device__ void phase4(const MP& p, int bid, int t, char* SMc){
  const int wv = t >> 6, lane = t & 63;
  if (bid < 256){
    unsigned short* h2 = (unsigned short*)SMc;       // [16*1032]
    float* red = (float*)(SMc + 33024);              // [4*64*4]
    {
      const int r = t >> 5, ll = t & 31;
      float4 vv[8];
      float s1 = 0.f, s2 = 0.f;
      #pragma unroll
      for (int i=0;i<8;i++){
        vv[i] = *(const float4*)(p.hid + (long)r*1024 + ll*32 + i*4);
        s1 += vv[i].x + vv[i].y + vv[i].z + vv[i].w;
        s2 += vv[i].x*vv[i].x + vv[i].y*vv[i].y + vv[i].z*vv[i].z + vv[i].w*vv[i].w;
      }
      #pragma unroll
      for (int m=1;m<32;m<<=1){ s1 += __shfl_xor(s1, m, 32); s2 += __shfl_xor(s2, m, 32); }
      const float mu  = s1 * (1.f/1024.f);
      const float var = s2 * (1.f/1024.f) - mu*mu;
      const float rs  = rsqrtf(var + 1e-5f);
      #pragma unroll
      for (int i=0;i<8;i++){
        const int e = ll*32 + i*4;
        const float4 g4 = *(const float4*)(p.lng + e);
        const float4 b4 = *(const float4*)(p.lnb + e);
        uint2 pk;
        pk.x = (unsigned)f2bf_rn((vv[i].x-mu)*rs*g4.x + b4.x) | ((unsigned)f2bf_rn((vv[i].y-mu)*rs*g4.y + b4.y) << 16);
        pk.y = (unsigned)f2bf_rn((vv[i].z-mu)*rs*g4.z + b4.z) | ((unsigned)f2bf_rn((vv[i].w-mu)*rs*g4.w + b4.w) << 16);
        *(uint2*)(h2 + r*1032 + e) = pk;
        *(uint2*)(h2 + (8+r)*1032 + e) = make_uint2(0u, 0u);
      }
    }
    __syncthreads();
    const int m16 = lane & 15, q = lane >> 4;
    const int j = bid*16 + m16;
    f32x4v a = {0.f,0.f,0.f,0.f};
    #pragma unroll
    for (int kt=0; kt<8; kt++){
      const int k = wv*256 + kt*32 + q*8;
      union { uint4 u; bf16x8 v; } A, B;
      A.u = *(const uint4*)(h2 + m16*1032 + k);
      const float4 f0 = *(const float4*)(p.W1 + (long)j*EE + k);
      const float4 f1 = *(const float4*)(p.W1 + (long)j*EE + k + 4);
      B.u.x = pk_hi(f0.x,f0.y); B.u.y = pk_hi(f0.z,f0.w);
      B.u.z = pk_hi(f1.x,f1.y); B.u.w = pk_hi(f1.z,f1.w);
      a = mfma16(A.v, B.v, a);
    }
    #pragma unroll
    for (int r=0;r<4;r++) red[(wv*64 + lane)*4 + r] = a[r];
    __syncthreads();
    if (wv == 0){
      #pragma unroll
      for (int r=0;r<4;r++){
        const float s = red[lane*4+r] + red[(64+lane)*4+r] + red[(128+lane)*4+r] + red[(192+lane)*4+r];
        const int row = q*4 + r;
        const float val = (row < 8) ? fmaxf(s + p.b1[j], 0.f) : 0.f;
        p.t1u[(long)row*4096 + j] = f2bf_rn(val);
      }
    }
  } else {
    float* sInv = (float*)SMc;
    const int idx2 = bid - 256;
    const int b = idx2 >> 5, seg = idx2 & 31;
    if (t < 16) sInv[t] = p.invD[b*16 + t];
    __syncthreads();
    if (t < 128){
      const int s = seg*128 + t;
      const float* wr = p.Wg + ((long)b*SS + s)*16;
      float a = 0.f;
      #pragma unroll
      for (int h=0;h<16;h++) a += wr[h]*sInv[h];
      p.out[40960 + (long)b*SS + s] = a;
    }
  }
}

// ---------------- P5: out += t1 @ W2^T (8-way grid k-split, atomic accumulate onto b2) ----------------
__device__ void phase5(const MP& p, int bid, int t, char* SMc){
  float* red = (float*)SMc;
  const int wv = t >> 6, lane = t & 63;
  const int m16 = lane & 15, q = lane >> 4;
  const int o = (bid & 63)*16 + m16;
  const int kbase = (bid >> 6)*512 + wv*128;
  f32x4v a = {0.f,0.f,0.f,0.f};
  #pragma unroll
  for (int kt=0; kt<4; kt++){
    const int k = kbase + kt*32 + q*8;
    union { uint4 u; bf16x8 v; } A, B;
    A.u = *(const uint4*)(p.t1u + (long)m16*4096 + k);
    const float4 f0 = *(const float4*)(p.W2 + (long)o*4096 + k);
    const float4 f1 = *(const float4*)(p.W2 + (long)o*4096 + k + 4);
    B.u.x = pk_hi(f0.x,f0.y); B.u.y = pk_hi(f0.z,f0.w);
    B.u.z = pk_hi(f1.x,f1.y); B.u.w = pk_hi(f1.z,f1.w);
    a = mfma16(A.v, B.v, a);
  }
  #pragma unroll
  for (int r=0;r<4;r++) red[(wv*64 + lane)*4 + r] = a[r];
  __syncthreads();
  if (wv == 0){
    #pragma unroll
    for (int r=0;r<4;r++){
      const int row = q*4 + r;
      if (row < 8){
        const float s = red[lane*4+r] + red[(64+lane)*4+r] + red[(128+lane)*4+r] + red[(192+lane)*4+r];
        atomicAdd(p.out + row*1024 + o, s);
      }
    }
  }
}

// ---------------- mega: cooperative, 512 blocks x 256 threads ----------------
__global__ __launch_bounds__(256,2) void mega(MP p){
  __shared__ __align__(16) char SMc[73408];
  cg::grid_group g = cg::this_grid();
  const int t = threadIdx.x, bid = blockIdx.x;
  phase0(p, bid, t);        g.sync();
  phase1(p, bid, t, SMc);   g.sync();
  phase2(p, bid, t, SMc);   g.sync();
  phase3(p, bid, t, SMc);   g.sync();
  phase4(p, bid, t, SMc);   g.sync();
  phase5(p, bid, t, SMc);
}

// ---------------- fallback: one plain kernel per phase ----------------
__global__ __launch_bounds__(256,2) void kp0(MP p){ phase0(p, blockIdx.x, threadIdx.x); }
__global__ __launch_bounds__(256,2) void kp1(MP p){ __shared__ __align__(16) char SMc[73408]; phase1(p, blockIdx.x, threadIdx.x, SMc); }
__global__ __launch_bounds__(256,2) void kp2(MP p){ __shared__ __align__(16) char SMc[73408]; phase2(p, blockIdx.x, threadIdx.x, SMc); }
__global__ __launch_bounds__(256,2) void kp3(MP p){ __shared__ __align__(16) char SMc[73408]; phase3(p, blockIdx.x, threadIdx.x, SMc); }
__global__ __launch_bounds__(256,2) void kp4(MP p){ __shared__ __align__(16) char SMc[73408]; phase4(p, blockIdx.x, threadIdx.x, SMc); }
__global__ __launch_bounds__(256,2) void kp5(MP p){ __shared__ __align__(16) char SMc[73408]; phase5(p, blockIdx.x, threadIdx.x, SMc); }

extern "C" void kernel_launch(void* const* d_in, const int* in_sizes, int n_in,
                              void* d_out, int out_size, void* d_ws, size_t ws_size,
                              hipStream_t stream){
  float* ws = (float*)d_ws;
  MP p;
  p.x    = (const float*)d_in[0];
  p.gum  = (const float*)d_in[1];
  p.query= (const float*)d_in[2];
  p.Wq   = (const float*)d_in[3];
  p.bq   = (const float*)d_in[4];
  p.Wk   = (const float*)d_in[5];
  p.bk   = (const float*)d_in[6];
  p.Wv   = (const float*)d_in[7];
  p.bv   = (const float*)d_in[8];
  p.lng  = (const float*)d_in[9];
  p.lnb  = (const float*)d_in[10];
  p.W1   = (const float*)d_in[11];
  p.b1   = (const float*)d_in[12];
  p.W2   = (const float*)d_in[13];
  p.b2   = (const float*)d_in[14];
  p.qvec = ws + OFF_QVEC;
  p.qkb  = ws + OFF_QKB;
  p.qh   = (unsigned short*)(ws + OFF_QH);
  p.ql   = (unsigned short*)(ws + OFF_QL);
  p.seC  = ws + OFF_SEC;
  p.saC  = ws + OFF_SAC;
  p.Wg   = ws + OFF_WG;
  p.hid  = ws + OFF_HID;
  p.t1u  = (unsigned short*)(ws + OFF_T1);
  p.invD = ws + OFF_INVD;
  p.psum = ws + OFF_PSUM;
  p.px   = (unsigned short*)(ws + OFF_PX);
  p.gth  = (double*)(ws + OFF_GTH);
  p.out  = (float*)d_out;

  void* args[] = { (void*)&p };
  hipError_t err = hipLaunchCooperativeKernel((const void*)mega, dim3(512), dim3(256), args, 0, stream);
  if (err != hipSuccess){
    (void)hipGetLastError();   // clear
    kp0<<<512, 256, 0, stream>>>(p);
    kp1<<<512, 256, 0, stream>>>(p);
    kp2<<<512, 256, 0, stream>>>(p);
    kp3<<<512, 256, 0, stream>>>(p);
    kp4<<<512, 256, 0, stream>>>(p);
    kp5<<<512, 256, 0, stream>>>(p);
  }
}

// Round 4
// 291.131 us; speedup vs baseline: 2.1205x; 2.1205x over previous
//
#include <hip/hip_runtime.h>
#include <hip/hip_bf16.h>
#include <math.h>

#define SS 4096
#define EE 1024
#define HH 16

typedef __bf16 bf16x8 __attribute__((ext_vector_type(8)));
typedef float  f32x4v __attribute__((ext_vector_type(4)));

// ws offsets (floats). total ~22.5 MB
#define OFF_QVEC 0L
#define OFF_QKB  1024L
#define OFF_QH   1040L      /* ushort[16*1024] = 8192 floats */
#define OFF_QL   9232L      /* ushort[16*1024] */
#define OFF_SEC  17424L     /* [8][16][256] = 32768 */
#define OFF_SAC  50192L     /* [8][16][256] = 32768 */
#define OFF_WG   82960L     /* [8][4096][16] = 524288 */
#define OFF_HID  607248L    /* 8192 */
#define OFF_T1   615440L    /* ushort[16*4096] = 32768 floats */
#define OFF_PX   648208L    /* ushort[8][64][16][1024] = 4194304 floats */
#define OFF_GTH  4842512L   /* double[8*16*4096] = 1048576 floats (even offset -> 8B aligned) */

__device__ __forceinline__ float bf2f(unsigned int u){
  union { unsigned int i; float f; } c; c.i = u << 16; return c.f;
}
__device__ __forceinline__ unsigned int pk_hi(float a, float b){
  return __builtin_amdgcn_perm(__float_as_uint(b), __float_as_uint(a), 0x07060302u);
}
__device__ __forceinline__ float lo_part(float f){
  return f - __uint_as_float(__float_as_uint(f) & 0xFFFF0000u);
}
__device__ __forceinline__ unsigned short f2bf_rn(float f){
  unsigned int u = __float_as_uint(f);
  return (unsigned short)((u + 0x7fffu + ((u >> 16) & 1u)) >> 16);
}
__device__ __forceinline__ f32x4v mfma16(bf16x8 a, bf16x8 b, f32x4v c){
  return __builtin_amdgcn_mfma_f32_16x16x32_bf16(a, b, c, 0, 0, 0);
}
__device__ __forceinline__ float waveRedSum(float v){
  #pragma unroll
  for (int m=1;m<64;m<<=1) v += __shfl_xor(v, m, 64);
  return v;
}
template<int NW>
__device__ __forceinline__ float blockRedSum(float v, volatile float* scr){
  v = waveRedSum(v);
  const int w = threadIdx.x >> 6;
  __syncthreads();
  if ((threadIdx.x & 63) == 0) scr[w] = v;
  __syncthreads();
  float r = 0.f;
  #pragma unroll
  for (int i=0;i<NW;i++) r += scr[i];
  return r;
}
__device__ __forceinline__ double gdiff(float u0, float u1){
  const double g0 = -log(-log((double)u0 + 1e-20) + 1e-20);
  const double g1 = -log(-log((double)u1 + 1e-20) + 1e-20);
  return g0 - g1;   // keep element iff (double)logit > gdiff
}

// ---------------- K1: qvec (blocks 0-255) | gth precompute + hid zero + out=b2 (blocks 256-767) ----------
__global__ __launch_bounds__(256) void k1(const float* __restrict__ query, const float* __restrict__ Wq,
                                          const float* __restrict__ bq, const float* __restrict__ gum,
                                          const float* __restrict__ b2,
                                          float* __restrict__ qvec, double* __restrict__ gth,
                                          float* __restrict__ hid, float* __restrict__ out){
  const int t = threadIdx.x;
  const int wv = t >> 6, lane = t & 63;
  const int bid = blockIdx.x;
  if (bid < 256){
    const int j = bid*4 + wv;
    float p = 0.f;
    #pragma unroll
    for (int i=0;i<4;i++){
      const int e = 4*lane + 256*i;
      const float4 q4 = *(const float4*)(query + e);
      const float4 w4 = *(const float4*)(Wq + (long)j*EE + e);
      p += q4.x*w4.x + q4.y*w4.y + q4.z*w4.z + q4.w*w4.w;
    }
    p = waveRedSum(p);
    if (lane == 0) qvec[j] = p + bq[j];
  } else {
    const int ib = bid - 256;           // 0..511
    if (ib < 32) hid[ib*256 + t] = 0.f;
    else if (ib < 64) out[(ib-32)*256 + t] = b2[((ib-32)&3)*256 + t];
    const long i0 = (long)ib*1024 + t*4;
    const float4 a4 = *(const float4*)(gum + 2*i0);
    const float4 b4 = *(const float4*)(gum + 2*i0 + 4);
    gth[i0+0] = gdiff(a4.x, a4.y);
    gth[i0+1] = gdiff(a4.z, a4.w);
    gth[i0+2] = gdiff(b4.x, b4.y);
    gth[i0+3] = gdiff(b4.z, b4.w);
  }
}

// ---------------- K2: qk split to bf16 hi/lo; qkb[h] ----------------
__global__ __launch_bounds__(256) void k2(const float* __restrict__ Wk, const float* __restrict__ bk,
                                          const float* __restrict__ qvec,
                                          unsigned short* __restrict__ qh, unsigned short* __restrict__ ql,
                                          float* __restrict__ qkb){
  __shared__ float red[4][64];
  const int wv = threadIdx.x >> 6, lane = threadIdx.x & 63;
  const int h = blockIdx.y;
  const int e = blockIdx.x*64 + lane;
  float acc = 0.f;
  #pragma unroll
  for (int dd=0; dd<16; dd++){
    const int d = wv*16 + dd;
    acc += qvec[h*64+d] * Wk[(long)(h*64+d)*EE + e];
  }
  red[wv][lane] = acc;
  __syncthreads();
  if (wv == 0){
    const float s = red[0][lane] + red[1][lane] + red[2][lane] + red[3][lane];
    const unsigned int ub = __float_as_uint(s);
    qh[h*EE + e] = (unsigned short)(ub >> 16);
    const float lo = s - __uint_as_float(ub & 0xFFFF0000u);
    ql[h*EE + e] = (unsigned short)(__float_as_uint(lo) >> 16);
    if (blockIdx.x == 0){
      float p = qvec[h*64+lane] * bk[h*64+lane];
      p = waveRedSum(p);
      if (lane == 0) qkb[h] = p;
    }
  }
}

// ---------------- K3F: fused logits(MFMA) + gumbel mask (precomputed gth) + chunk sums + aggregation ------
// grid (64 sblk, 8 b), 256 threads. Block handles 64 s = 4 chunks of 16.
// LDS xsT rows = e (64 B), cols interleaved: word m16 of row e = (hi(x[s=m16][e]) | lo(x)<<16).
// K=32 mapping: slot 2s = x_hi[s], slot 2s+1 = x_lo[s]; B operands duplicate w per pair -> exact sum.
__global__ __launch_bounds__(256,2) void k3f(const float* __restrict__ x, const double* __restrict__ gth,
                                             const unsigned short* __restrict__ qh, const unsigned short* __restrict__ ql,
                                             const float* __restrict__ qkb,
                                             float* __restrict__ seC, float* __restrict__ saC,
                                             float* __restrict__ Wg, unsigned short* __restrict__ px,
                                             float* __restrict__ out){
  __shared__ unsigned int xsT[4][256*16];    // per-wave [e 256][16 words] = 64 KB total
  __shared__ float lg[4*16*17];
  __shared__ float wT[16][20];               // [h][s]
  __shared__ float scrA[16*17], scrB[16*17];
  __shared__ float sQkb[16];
  const int t = threadIdx.x;
  const int wv = t >> 6, lane = t & 63;
  const int m16 = lane & 15, q = lane >> 4;
  const int blk = blockIdx.x, b = blockIdx.y;
  if (t < 16) sQkb[t] = qkb[t];
  unsigned int* xw32 = &xsT[wv][0];
  const unsigned short* xw16 = (const unsigned short*)xw32;

  f32x4v P[16];
  #pragma unroll
  for (int i=0;i<16;i++){ P[i][0]=0.f; P[i][1]=0.f; P[i][2]=0.f; P[i][3]=0.f; }

  for (int ch=0; ch<4; ch++){
    const int c = blk*4 + ch;
    const long xbase = ((long)(b*SS + c*16))*EE;

    // phase 1: logits via split-bf16 MFMA; stage interleaved hi/lo into xsT
    f32x4v a = {0.f,0.f,0.f,0.f};
    #pragma unroll
    for (int kt=0; kt<8; kt++){
      const int k = wv*256 + kt*32 + q*8;
      const float* xp = x + xbase + (long)m16*EE + k;
      const float4 f0 = *(const float4*)(xp);
      const float4 f1 = *(const float4*)(xp + 4);
      union { uint4 u; bf16x8 v; } xh, xl, bh, bl;
      xh.u.x = pk_hi(f0.x, f0.y); xh.u.y = pk_hi(f0.z, f0.w);
      xh.u.z = pk_hi(f1.x, f1.y); xh.u.w = pk_hi(f1.z, f1.w);
      xl.u.x = pk_hi(lo_part(f0.x), lo_part(f0.y)); xl.u.y = pk_hi(lo_part(f0.z), lo_part(f0.w));
      xl.u.z = pk_hi(lo_part(f1.x), lo_part(f1.y)); xl.u.w = pk_hi(lo_part(f1.z), lo_part(f1.w));
      bh.u = *(const uint4*)(qh + (long)m16*EE + k);
      bl.u = *(const uint4*)(ql + (long)m16*EE + k);
      a = mfma16(xh.v, bh.v, a);
      a = mfma16(xh.v, bl.v, a);
      a = mfma16(xl.v, bh.v, a);
      // scatter: one interleaved u32 per e (hi | lo<<16); rows 64 B, word col = m16
      const unsigned hw[4] = {xh.u.x, xh.u.y, xh.u.z, xh.u.w};
      const unsigned lw[4] = {xl.u.x, xl.u.y, xl.u.z, xl.u.w};
      const int rowbase = (kt*32 + q*8)*16 + m16;
      #pragma unroll
      for (int jj=0; jj<8; jj++){
        const unsigned val = __builtin_amdgcn_perm(lw[jj>>1], hw[jj>>1],
                                                   (jj & 1) ? 0x07060302u : 0x05040100u);
        xw32[rowbase + jj*16] = val;
      }
    }
    #pragma unroll
    for (int r=0;r<4;r++)
      lg[(wv*16 + q*4 + r)*17 + m16] = a[r];
    __syncthreads();

    // phase 2: logit assembly + precomputed gumbel threshold
    {
      const int h = t & 15, s = t >> 4;
      const float dot = lg[s*17+h] + lg[(16+s)*17+h] + lg[(32+s)*17+h] + lg[(48+s)*17+h];
      const float logit = (dot + sQkb[h]) * 0.125f;
      const long gi = ((long)(b*16 + h))*SS + c*16 + s;
      const double gthd = gth[gi];
      const float e = expf(logit);
      const float wval = ((double)logit > gthd) ? e : 0.f;
      wT[h][s] = wval;
      Wg[((long)b*SS + c*16 + s)*16 + h] = wval;
      scrA[s*17 + h] = e;
      scrB[s*17 + h] = wval;
    }
    __syncthreads();

    // tail A: per-chunk sums + mask counts
    if (t < 16){
      float S = 0.f, SA = 0.f, cnt = 0.f;
      #pragma unroll
      for (int i=0;i<16;i++){ S += scrA[i*17 + t]; SA += scrB[i*17 + t]; }
      #pragma unroll
      for (int hh=0; hh<16; hh++) cnt += (scrB[t*17 + hh] > 0.f) ? 1.f : 0.f;
      seC[((long)(b*16 + t))*256 + c] = S;
      saC[((long)(b*16 + t))*256 + c] = SA;
      out[8192 + (long)b*SS + c*16 + t] = cnt;
    }

    // tail B: aggregation MFMA. A slots interleaved (hi,lo); B duplicates w[s] per pair.
    {
      const float4 w4 = *(const float4*)&wT[m16][q*4];
      union { uint4 u; bf16x8 v; } B1, B2;
      B1.u.x = pk_hi(w4.x, w4.x); B1.u.y = pk_hi(w4.y, w4.y);
      B1.u.z = pk_hi(w4.z, w4.z); B1.u.w = pk_hi(w4.w, w4.w);
      const float l0 = lo_part(w4.x), l1 = lo_part(w4.y), l2 = lo_part(w4.z), l3 = lo_part(w4.w);
      B2.u.x = pk_hi(l0, l0); B2.u.y = pk_hi(l1, l1);
      B2.u.z = pk_hi(l2, l2); B2.u.w = pk_hi(l3, l3);
      #pragma unroll
      for (int et=0; et<16; et++){
        union { uint4 u; bf16x8 v; } A;
        A.u = *(const uint4*)(xw16 + (et*16 + m16)*32 + q*8);
        P[et] = mfma16(A.v, B1.v, P[et]);
        P[et] = mfma16(A.v, B2.v, P[et]);
      }
    }
  }

  // store bf16 partials: px[b][blk][h=m16][e = wv*256 + et*16 + q*4 + r]
  const long pbase = (((long)(b*64 + blk))*16 + m16)*1024 + wv*256;
  #pragma unroll
  for (int et=0; et<16; et++){
    uint2 pk2;
    pk2.x = (unsigned)f2bf_rn(P[et][0]) | ((unsigned)f2bf_rn(P[et][1]) << 16);
    pk2.y = (unsigned)f2bf_rn(P[et][2]) | ((unsigned)f2bf_rn(P[et][3]) << 16);
    *(uint2*)(px + pbase + et*16 + q*4) = pk2;
  }
}

// ---------------- KB: invD/psum + attn-out + px-reduce + hid = xa.Wv*invD + psum*bv (atomics) --------
// grid: 32 attn blocks + 512 hid blocks (b,h,equarter)
__global__ __launch_bounds__(256) void kb(const unsigned short* __restrict__ px, const float* __restrict__ Wg,
                                          const float* __restrict__ seC, const float* __restrict__ saC,
                                          const float* __restrict__ Wv, const float* __restrict__ bv,
                                          float* __restrict__ hid, float* __restrict__ out){
  __shared__ float s_red[16][17];
  __shared__ float sInv[16];
  __shared__ float scr1[4], scr2[4];
  __shared__ float xs[256];
  const int t = threadIdx.x;

  if (blockIdx.x < 32){
    const int b = blockIdx.x >> 2, sq = blockIdx.x & 3;
    { const int h = t >> 4, cl = t & 15;
      float se = 0.f;
      #pragma unroll
      for (int k=0;k<16;k++) se += seC[((long)(b*16+h))*256 + cl + 16*k];
      s_red[h][cl] = se;
    }
    __syncthreads();
    if (t < 16){
      float D = 0.f;
      #pragma unroll
      for (int i=0;i<16;i++) D += s_red[t][i];
      sInv[t] = 1.f / D;
    }
    __syncthreads();
    #pragma unroll
    for (int it=0; it<4; it++){
      const int s = sq*1024 + it*256 + t;
      const float* wr = Wg + ((long)b*SS + s)*16;
      float a = 0.f;
      #pragma unroll
      for (int h=0;h<16;h++) a += wr[h]*sInv[h];
      out[40960 + (long)b*SS + s] = a;
    }
    return;
  }

  const int idx = blockIdx.x - 32;
  const int b = idx >> 6, h = (idx >> 2) & 15, eq = idx & 3;
  const long rbase = ((long)(b*16 + h))*256;
  const float D    = blockRedSum<4>(seC[rbase + t], scr1);
  const float SA   = blockRedSum<4>(saC[rbase + t], scr2);
  const float invD = 1.f / D;
  const float psum = SA * invD;
  const unsigned short* pp = px + (((long)(b*64))*16 + h)*1024 + eq*256 + t;
  float xa = 0.f;
  #pragma unroll 8
  for (int seg=0; seg<64; seg++) xa += bf2f((unsigned)pp[(long)seg*16384]);
  xs[t] = xa;
  __syncthreads();
  const int wv = t >> 6, lane = t & 63;
  const float4 xv = *(const float4*)(xs + 4*lane);
  #pragma unroll 4
  for (int jj=0; jj<16; jj++){
    const int j = h*64 + wv*16 + jj;
    const float4 w4 = *(const float4*)(Wv + (long)j*EE + eq*256 + 4*lane);
    float pr = xv.x*w4.x + xv.y*w4.y + xv.z*w4.z + xv.w*w4.w;
    pr = waveRedSum(pr);
    if (lane == 0){
      float add = pr * invD;
      if (eq == 0) add += psum * bv[j];
      atomicAdd(&hid[(long)b*EE + j], add);
    }
  }
}

// ---------------- K8F: LayerNorm (in-LDS) + t1 = relu(h2 @ W1^T + b1) ----------------
__global__ __launch_bounds__(256) void k8f(const float* __restrict__ hid, const float* __restrict__ lng,
                                           const float* __restrict__ lnb, const float* __restrict__ W1,
                                           const float* __restrict__ b1,
                                           unsigned short* __restrict__ t1u){
  __shared__ unsigned short h2[16*1032];
  __shared__ float red[4*64*4];
  const int t = threadIdx.x;
  {
    const int r = t >> 5, ll = t & 31;
    float4 vv[8];
    float s1 = 0.f, s2 = 0.f;
    #pragma unroll
    for (int i=0;i<8;i++){
      vv[i] = *(const float4*)(hid + (long)r*1024 + ll*32 + i*4);
      s1 += vv[i].x + vv[i].y + vv[i].z + vv[i].w;
      s2 += vv[i].x*vv[i].x + vv[i].y*vv[i].y + vv[i].z*vv[i].z + vv[i].w*vv[i].w;
    }
    #pragma unroll
    for (int m=1;m<32;m<<=1){ s1 += __shfl_xor(s1, m, 32); s2 += __shfl_xor(s2, m, 32); }
    const float mu  = s1 * (1.f/1024.f);
    const float var = s2 * (1.f/1024.f) - mu*mu;
    const float rs  = rsqrtf(var + 1e-5f);
    #pragma unroll
    for (int i=0;i<8;i++){
      const int e = ll*32 + i*4;
      const float4 g4 = *(const float4*)(lng + e);
      const float4 b4 = *(const float4*)(lnb + e);
      uint2 pk;
      pk.x = (unsigned)f2bf_rn((vv[i].x-mu)*rs*g4.x + b4.x) | ((unsigned)f2bf_rn((vv[i].y-mu)*rs*g4.y + b4.y) << 16);
      pk.y = (unsigned)f2bf_rn((vv[i].z-mu)*rs*g4.z + b4.z) | ((unsigned)f2bf_rn((vv[i].w-mu)*rs*g4.w + b4.w) << 16);
      *(uint2*)(h2 + r*1032 + e) = pk;
      *(uint2*)(h2 + (8+r)*1032 + e) = make_uint2(0u, 0u);
    }
  }
  __syncthreads();
  const int wv = t >> 6, lane = t & 63;
  const int m16 = lane & 15, q = lane >> 4;
  const int j = blockIdx.x*16 + m16;
  f32x4v a = {0.f,0.f,0.f,0.f};
  #pragma unroll
  for (int kt=0; kt<8; kt++){
    const int k = wv*256 + kt*32 + q*8;
    union { uint4 u; bf16x8 v; } A, B;
    A.u = *(const uint4*)(h2 + m16*1032 + k);
    const float4 f0 = *(const float4*)(W1 + (long)j*EE + k);
    const float4 f1 = *(const float4*)(W1 + (long)j*EE + k + 4);
    B.u.x = pk_hi(f0.x,f0.y); B.u.y = pk_hi(f0.z,f0.w);
    B.u.z = pk_hi(f1.x,f1.y); B.u.w = pk_hi(f1.z,f1.w);
    a = mfma16(A.v, B.v, a);
  }
  #pragma unroll
  for (int r=0;r<4;r++) red[(wv*64 + lane)*4 + r] = a[r];
  __syncthreads();
  if (wv == 0){
    #pragma unroll
    for (int r=0;r<4;r++){
      const float s = red[lane*4+r] + red[(64+lane)*4+r] + red[(128+lane)*4+r] + red[(192+lane)*4+r];
      const int row = q*4 + r;
      const float val = (row < 8) ? fmaxf(s + b1[j], 0.f) : 0.f;
      t1u[(long)row*4096 + j] = f2bf_rn(val);
    }
  }
}

// ---------------- K9A: out += t1 @ W2^T (MFMA, grid k-split 4 x wave k-split 4, atomic accumulate) --------
__global__ __launch_bounds__(256) void k9a(const unsigned short* __restrict__ t1u, const float* __restrict__ W2,
                                           float* __restrict__ out){
  __shared__ float red[4*64*4];
  const int wv = threadIdx.x >> 6, lane = threadIdx.x & 63;
  const int m16 = lane & 15, q = lane >> 4;
  const int o = blockIdx.x*16 + m16;
  const int kbase = blockIdx.y*1024 + wv*256;
  f32x4v a = {0.f,0.f,0.f,0.f};
  #pragma unroll
  for (int kt=0; kt<8; kt++){
    const int k = kbase + kt*32 + q*8;
    union { uint4 u; bf16x8 v; } A, B;
    A.u = *(const uint4*)(t1u + (long)m16*4096 + k);
    const float4 f0 = *(const float4*)(W2 + (long)o*4096 + k);
    const float4 f1 = *(const float4*)(W2 + (long)o*4096 + k + 4);
    B.u.x = pk_hi(f0.x,f0.y); B.u.y = pk_hi(f0.z,f0.w);
    B.u.z = pk_hi(f1.x,f1.y); B.u.w = pk_hi(f1.z,f1.w);
    a = mfma16(A.v, B.v, a);
  }
  #pragma unroll
  for (int r=0;r<4;r++) red[(wv*64 + lane)*4 + r] = a[r];
  __syncthreads();
  if (wv == 0){
    #pragma unroll
    for (int r=0;r<4;r++){
      const int row = q*4 + r;
      if (row < 8){
        const float s = red[lane*4+r] + red[(64+lane)*4+r] + red[(128+lane)*4+r] + red[(192+lane)*4+r];
        atomicAdd(out + row*1024 + o, s);
      }
    }
  }
}

extern "C" void kernel_launch(void* const* d_in, const int* in_sizes, int n_in,
                              void* d_out, int out_size, void* d_ws, size_t ws_size,
                              hipStream_t stream){
  const float* x    = (const float*)d_in[0];
  const float* gum  = (const float*)d_in[1];
  const float* query= (const float*)d_in[2];
  const float* Wq   = (const float*)d_in[3];
  const float* bq   = (const float*)d_in[4];
  const float* Wk   = (const float*)d_in[5];
  const float* bk   = (const float*)d_in[6];
  const float* Wv   = (const float*)d_in[7];
  const float* bv   = (const float*)d_in[8];
  const float* lng  = (const float*)d_in[9];
  const float* lnb  = (const float*)d_in[10];
  const float* W1   = (const float*)d_in[11];
  const float* b1   = (const float*)d_in[12];
  const float* W2   = (const float*)d_in[13];
  const float* b2   = (const float*)d_in[14];
  float* ws = (float*)d_ws;
  float* qvec = ws + OFF_QVEC;
  float* qkb  = ws + OFF_QKB;
  unsigned short* qh = (unsigned short*)(ws + OFF_QH);
  unsigned short* ql = (unsigned short*)(ws + OFF_QL);
  float* seC  = ws + OFF_SEC;
  float* saC  = ws + OFF_SAC;
  float* Wg   = ws + OFF_WG;
  float* hid  = ws + OFF_HID;
  unsigned short* t1u = (unsigned short*)(ws + OFF_T1);
  unsigned short* px  = (unsigned short*)(ws + OFF_PX);
  double* gth = (double*)(ws + OFF_GTH);
  float* out = (float*)d_out;

  k1  <<<768, 256, 0, stream>>>(query, Wq, bq, gum, b2, qvec, gth, hid, out);
  k2  <<<dim3(16,16), 256, 0, stream>>>(Wk, bk, qvec, qh, ql, qkb);
  k3f <<<dim3(64,8), 256, 0, stream>>>(x, gth, qh, ql, qkb, seC, saC, Wg, px, out);
  kb  <<<544, 256, 0, stream>>>(px, Wg, seC, saC, Wv, bv, hid, out);
  k8f <<<256, 256, 0, stream>>>(hid, lng, lnb, W1, b1, t1u);
  k9a <<<dim3(64,4), 256, 0, stream>>>(t1u, W2, out);
}